// Round 1
// baseline (232.171 us; speedup 1.0000x reference)
//
#include <hip/hip_runtime.h>
#include <hip/hip_bf16.h>
#include <cstdint>
#include <cstddef>

#define BATCH 8192
#define IDIM  768
#define JDIM  768
#define GRID  5
#define KDIM  (IDIM * GRID)   // 3840

// ---------------- helpers ----------------

__device__ __forceinline__ unsigned short f2bf(float f) {
    // round-to-nearest-even fp32 -> bf16 bits (inputs here are finite)
    unsigned int u = __float_as_uint(f);
    unsigned int lsb = (u >> 16) & 1u;
    u += 0x7fffu + lsb;
    return (unsigned short)(u >> 16);
}

typedef __bf16 bf16x8 __attribute__((ext_vector_type(8)));
typedef float  f32x4  __attribute__((ext_vector_type(4)));

__device__ __forceinline__ void async_copy16(const void* gsrc, void* ldsdst) {
    __builtin_amdgcn_global_load_lds(
        (const __attribute__((address_space(1))) unsigned int*)gsrc,
        (__attribute__((address_space(3))) unsigned int*)ldsdst,
        16, 0, 0);
}

// ---------------- precompute kernels ----------------

// Wt[j][g*768 + i] = bf16(coeffs[i,j,g] * scale[i,j])
__global__ void wt_kernel(const float* __restrict__ coeffs,
                          const float* __restrict__ scale,
                          unsigned short* __restrict__ Wt) {
    int idx = blockIdx.x * blockDim.x + threadIdx.x;
    if (idx >= JDIM * IDIM) return;
    int j = idx / IDIM;
    int i = idx - j * IDIM;
    float sc = scale[(size_t)i * JDIM + j];
    const float* cp = &coeffs[((size_t)i * JDIM + j) * GRID];
#pragma unroll
    for (int g = 0; g < GRID; ++g) {
        Wt[(size_t)j * KDIM + g * IDIM + i] = f2bf(cp[g] * sc);
    }
}

// bias[j] = sum_i shift[i,j]
__global__ void bias_kernel(const float* __restrict__ shift,
                            float* __restrict__ bias) {
    int j = blockIdx.x * blockDim.x + threadIdx.x;
    if (j >= JDIM) return;
    float s = 0.f;
    for (int i = 0; i < IDIM; ++i) s += shift[(size_t)i * JDIM + j];
    bias[j] = s;
}

// Abas[b][g*768 + i] = bf16(exp(-5*(tanh(x[b,i]) - grid[g])^2))
__global__ void basis_kernel(const float* __restrict__ x,
                             unsigned short* __restrict__ Abas) {
    int idx = blockIdx.x * blockDim.x + threadIdx.x;
    if (idx >= BATCH * IDIM) return;
    int b = idx / IDIM;
    int i = idx - b * IDIM;
    float tv = tanhf(x[idx]);
#pragma unroll
    for (int g = 0; g < GRID; ++g) {
        float d = tv - (-1.0f + 0.5f * (float)g);
        Abas[(size_t)b * KDIM + g * IDIM + i] = f2bf(__expf(-5.0f * d * d));
    }
}

// ---------------- MFMA GEMM ----------------
// C[8192,768] = Abas[8192,3840](bf16) @ Wt^T  + bias
// Tiles: BM=128, BN=128, BK=64. 256 threads = 4 waves, each wave a 64x64 sub-tile.

#define BM 128
#define BN 128
#define BK 64

__global__ __launch_bounds__(256, 2)
void kan_gemm(const unsigned short* __restrict__ Abas,  // [BATCH][KDIM]
              const unsigned short* __restrict__ Wt,    // [JDIM][KDIM]  (W transposed, k contiguous)
              const float* __restrict__ bias,           // [JDIM]
              float* __restrict__ out) {                // [BATCH][JDIM]
    __shared__ unsigned short As[BM * BK];  // [m][k] row-major, 16 KB
    __shared__ unsigned short Bs[BN * BK];  // [n][k] row-major, 16 KB

    const int t    = threadIdx.x;
    const int lane = t & 63;
    const int wave = t >> 6;
    const int m0 = blockIdx.y * BM;
    const int n0 = blockIdx.x * BN;
    const int wm = (wave >> 1) * 64;   // wave row offset inside block tile
    const int wn = (wave & 1) * 64;    // wave col offset

    f32x4 acc[4][4] = {};

    // staging geometry: thread t loads 16B at LDS byte offset t*16
    const int lrow = t >> 3;          // 0..31 (tile row per issue)
    const int lcol = (t & 7) * 8;     // element offset along k

    for (int kt = 0; kt < KDIM; kt += BK) {
#pragma unroll
        for (int s = 0; s < 4; ++s) {
            async_copy16(&Abas[(size_t)(m0 + lrow + 32 * s) * KDIM + kt + lcol],
                         &As[(lrow + 32 * s) * BK + lcol]);
        }
#pragma unroll
        for (int s = 0; s < 4; ++s) {
            async_copy16(&Wt[(size_t)(n0 + lrow + 32 * s) * KDIM + kt + lcol],
                         &Bs[(lrow + 32 * s) * BK + lcol]);
        }
        asm volatile("s_waitcnt vmcnt(0)" ::: "memory");
        __syncthreads();

#pragma unroll
        for (int ks = 0; ks < 2; ++ks) {
            bf16x8 af[4], bfr[4];
#pragma unroll
            for (int f = 0; f < 4; ++f) {
                af[f]  = *(const bf16x8*)&As[(wm + f * 16 + (lane & 15)) * BK + ks * 32 + (lane >> 4) * 8];
                bfr[f] = *(const bf16x8*)&Bs[(wn + f * 16 + (lane & 15)) * BK + ks * 32 + (lane >> 4) * 8];
            }
#pragma unroll
            for (int fm = 0; fm < 4; ++fm) {
#pragma unroll
                for (int fn = 0; fn < 4; ++fn) {
                    acc[fm][fn] = __builtin_amdgcn_mfma_f32_16x16x32_bf16(
                        af[fm], bfr[fn], acc[fm][fn], 0, 0, 0);
                }
            }
        }
        __syncthreads();
    }

    // epilogue: D mapping col=lane&15, row=(lane>>4)*4+reg  [measured m89/m91]
    const int col   = lane & 15;
    const int rbase = (lane >> 4) * 4;
#pragma unroll
    for (int fm = 0; fm < 4; ++fm) {
#pragma unroll
        for (int fn = 0; fn < 4; ++fn) {
            const int j  = n0 + wn + fn * 16 + col;
            const float bj = bias[j];
#pragma unroll
            for (int r = 0; r < 4; ++r) {
                const int row = m0 + wm + fm * 16 + rbase + r;
                out[(size_t)row * JDIM + j] = acc[fm][fn][r] + bj;
            }
        }
    }
}

// ---------------- fallback (ws too small): slow but correct ----------------

__global__ __launch_bounds__(256)
void fallback_kernel(const float* __restrict__ x,
                     const float* __restrict__ coeffs,
                     const float* __restrict__ scale,
                     const float* __restrict__ shift,
                     float* __restrict__ out) {
    __shared__ float bas[KDIM];
    const int b = blockIdx.x;
    const int t = threadIdx.x;
    for (int i = t; i < IDIM; i += 256) {
        float tv = tanhf(x[(size_t)b * IDIM + i]);
#pragma unroll
        for (int g = 0; g < GRID; ++g) {
            float d = tv - (-1.0f + 0.5f * (float)g);
            bas[g * IDIM + i] = __expf(-5.0f * d * d);
        }
    }
    __syncthreads();
#pragma unroll
    for (int jj = 0; jj < 3; ++jj) {
        const int j = t + jj * 256;
        float acc = 0.f;
        for (int i = 0; i < IDIM; ++i) {
            const float sc = scale[(size_t)i * JDIM + j];
            const float* cp = &coeffs[((size_t)i * JDIM + j) * GRID];
            float s5 = 0.f;
#pragma unroll
            for (int g = 0; g < GRID; ++g) s5 += bas[g * IDIM + i] * cp[g];
            acc += s5 * sc + shift[(size_t)i * JDIM + j];
        }
        out[(size_t)b * JDIM + j] = acc;
    }
}

// ---------------- launch ----------------

extern "C" void kernel_launch(void* const* d_in, const int* in_sizes, int n_in,
                              void* d_out, int out_size, void* d_ws, size_t ws_size,
                              hipStream_t stream) {
    const float* x      = (const float*)d_in[0];
    const float* coeffs = (const float*)d_in[1];
    const float* scale  = (const float*)d_in[2];
    const float* shift  = (const float*)d_in[3];
    float* out = (float*)d_out;

    const size_t wt_bytes   = (size_t)JDIM * KDIM * sizeof(unsigned short); // 5,898,240
    const size_t bias_off   = wt_bytes;                                     // 16B aligned
    const size_t bias_bytes = (size_t)JDIM * sizeof(float);                 // 3,072
    const size_t bas_off    = bias_off + bias_bytes;                        // 16B aligned
    const size_t bas_bytes  = (size_t)BATCH * KDIM * sizeof(unsigned short);// 62,914,560
    const size_t need       = bas_off + bas_bytes;                          // ~68.8 MB

    if (ws_size >= need) {
        unsigned short* Wt   = (unsigned short*)d_ws;
        float*          bias = (float*)((char*)d_ws + bias_off);
        unsigned short* Abas = (unsigned short*)((char*)d_ws + bas_off);

        wt_kernel<<<(JDIM * IDIM + 255) / 256, 256, 0, stream>>>(coeffs, scale, Wt);
        bias_kernel<<<3, 256, 0, stream>>>(shift, bias);
        basis_kernel<<<(BATCH * IDIM + 255) / 256, 256, 0, stream>>>(x, Abas);
        kan_gemm<<<dim3(JDIM / BN, BATCH / BM), 256, 0, stream>>>(Abas, Wt, bias, out);
    } else {
        fallback_kernel<<<BATCH, 256, 0, stream>>>(x, coeffs, scale, shift, out);
    }
}

// Round 2
// 172.653 us; speedup vs baseline: 1.3447x; 1.3447x over previous
//
#include <hip/hip_runtime.h>
#include <hip/hip_bf16.h>
#include <cstdint>
#include <cstddef>

#define BATCH 8192
#define IDIM  768
#define JDIM  768
#define GRID  5
#define KDIM  (IDIM * GRID)   // 3840

// ---------------- helpers ----------------

__device__ __forceinline__ unsigned short f2bf(float f) {
    // round-to-nearest-even fp32 -> bf16 bits (inputs here are finite)
    unsigned int u = __float_as_uint(f);
    u += 0x7fffu + ((u >> 16) & 1u);
    return (unsigned short)(u >> 16);
}

typedef __bf16 bf16x8 __attribute__((ext_vector_type(8)));
typedef float  f32x4  __attribute__((ext_vector_type(4)));
typedef unsigned short ushortx4 __attribute__((ext_vector_type(4)));

__device__ __forceinline__ void async_copy16(const void* gsrc, void* ldsdst) {
    __builtin_amdgcn_global_load_lds(
        (const __attribute__((address_space(1))) unsigned int*)gsrc,
        (__attribute__((address_space(3))) unsigned int*)ldsdst,
        16, 0, 0);
}

// ---------------- precompute: Wt + bias (fused, LDS transpose) ----------------
// Wt[j][g*768+i] = bf16(coeffs[i,j,g]*scale[i,j]);  bias[j] += sum_i shift[i,j]
// Tile: 32 i x 64 j. Reads coalesced over j; writes coalesced over i (ushort4).

#define WT_I 32
#define WT_J 64

__global__ __launch_bounds__(256)
void wt_bias_kernel(const float* __restrict__ coeffs,
                    const float* __restrict__ scale,
                    const float* __restrict__ shift,
                    unsigned short* __restrict__ Wt,
                    float* __restrict__ bias) {
    __shared__ __align__(16) unsigned short tile[GRID][WT_J][WT_I + 4]; // pad->36 (72B rows, 8B aligned)
    __shared__ float red[4][WT_J];
    const int t  = threadIdx.x;
    const int i0 = (blockIdx.x / (JDIM / WT_J)) * WT_I;
    const int j0 = (blockIdx.x % (JDIM / WT_J)) * WT_J;
    const int jj = t & 63;

    float ssum = 0.f;
#pragma unroll
    for (int it = 0; it < (WT_I * WT_J) / 256; ++it) {          // 8 iters
        const int ii = it * 4 + (t >> 6);
        const int i = i0 + ii, j = j0 + jj;
        const float* cp = &coeffs[((size_t)i * JDIM + j) * GRID];
        const float  sc = scale[(size_t)i * JDIM + j];
        ssum += shift[(size_t)i * JDIM + j];
#pragma unroll
        for (int g = 0; g < GRID; ++g)
            tile[g][jj][ii] = f2bf(cp[g] * sc);
    }
    red[t >> 6][jj] = ssum;
    __syncthreads();
    if (t < WT_J)
        atomicAdd(&bias[j0 + t], red[0][t] + red[1][t] + red[2][t] + red[3][t]);

    // write out: 64j * 5g * 8 ushort4 = 2560 stores / 256 threads = 10 iters
#pragma unroll
    for (int it = 0; it < (WT_J * GRID * (WT_I / 4)) / 256; ++it) {
        const int p  = it * 256 + t;
        const int iq = p & 7;
        const int q  = p >> 3;
        const int g  = q % GRID;
        const int j  = q / GRID;
        ushortx4 v = *(const ushortx4*)&tile[g][j][iq * 4];
        *(ushortx4*)&Wt[(size_t)(j0 + j) * KDIM + g * IDIM + i0 + iq * 4] = v;
    }
}

// ---------------- precompute: basis ----------------
// Abas[b][g*768+i] = bf16(exp(-5*(tanh(x[b,i]) - grid[g])^2)); 4 i's per thread.

__global__ __launch_bounds__(256)
void basis_kernel(const float* __restrict__ x, unsigned short* __restrict__ Abas) {
    const int idx = blockIdx.x * 256 + threadIdx.x;           // over BATCH*192, exact
    const int b  = idx / (IDIM / 4);
    const int i4 = (idx - b * (IDIM / 4)) * 4;
    const float4 xv = *(const float4*)&x[(size_t)b * IDIM + i4];
    const float xs[4] = {xv.x, xv.y, xv.z, xv.w};
    float tv[4];
#pragma unroll
    for (int u = 0; u < 4; ++u) {
        // tanh(x) = 1 - 2/(e^{2x}+1); saturates correctly at +-inf
        const float e = __expf(2.f * xs[u]);
        tv[u] = 1.f - 2.f / (e + 1.f);
    }
#pragma unroll
    for (int g = 0; g < GRID; ++g) {
        const float gv = -1.f + 0.5f * (float)g;
        ushortx4 o;
#pragma unroll
        for (int u = 0; u < 4; ++u) {
            const float d = tv[u] - gv;
            o[u] = f2bf(__expf(-5.f * d * d));
        }
        *(ushortx4*)&Abas[(size_t)b * KDIM + g * IDIM + i4] = o;
    }
}

// ---------------- MFMA GEMM ----------------
// C[8192,768] = Abas @ Wt^T + bias.  BM=128, BN=96, BK=64.
// Grid = 8 x 64 = 512 blocks -> exactly 2 blocks/CU (balanced).
// XOR k-chunk swizzle so ds_read_b128 fragment reads spread over all 32 banks.

#define BM 128
#define BN 96
#define BK 64

__global__ __launch_bounds__(256, 2)
void kan_gemm(const unsigned short* __restrict__ Abas,  // [BATCH][KDIM]
              const unsigned short* __restrict__ Wt,    // [JDIM][KDIM]
              const float* __restrict__ bias,           // [JDIM]
              float* __restrict__ out) {                // [BATCH][JDIM]
    __shared__ unsigned short As[BM * BK];  // 16 KB, [m][k] XOR-swizzled in 8-elem chunks
    __shared__ unsigned short Bs[BN * BK];  // 12 KB

    const int t    = threadIdx.x;
    const int lane = t & 63;
    const int wave = t >> 6;
    const int m0 = blockIdx.y * BM;
    const int n0 = blockIdx.x * BN;
    const int wm = (wave >> 1) * 64;   // 0 / 64
    const int wn = (wave & 1) * 48;    // 0 / 48

    f32x4 acc[4][3] = {};

    // staging: thread t owns LDS slot (row=t>>3, chunk=t&7) = bytes t*16.
    // source chunk is XOR-swizzled: LDS[r][c] holds global chunk c^(r&7).
    const int lrow = t >> 3;
    const int lc   = t & 7;
    const int cg   = lc ^ (lrow & 7);
    const int ldsoff = lrow * BK + lc * 8;                 // elements
    const size_t abase = (size_t)(m0 + lrow) * KDIM + cg * 8;
    const size_t bbase = (size_t)(n0 + lrow) * KDIM + cg * 8;

    for (int kt = 0; kt < KDIM; kt += BK) {
#pragma unroll
        for (int s = 0; s < 4; ++s)
            async_copy16(&Abas[abase + (size_t)(32 * s) * KDIM + kt], &As[ldsoff + 32 * s * BK]);
#pragma unroll
        for (int s = 0; s < 3; ++s)
            async_copy16(&Wt[bbase + (size_t)(32 * s) * KDIM + kt], &Bs[ldsoff + 32 * s * BK]);
        asm volatile("s_waitcnt vmcnt(0)" ::: "memory");
        __syncthreads();

#pragma unroll
        for (int ks = 0; ks < 2; ++ks) {
            // logical chunk = ks*4 + (lane>>4); row&7 == lane&7 for all fragment rows
            const int pc = ((ks * 4) + (lane >> 4)) ^ (lane & 7);
            bf16x8 af[4], bfr[3];
#pragma unroll
            for (int f = 0; f < 4; ++f)
                af[f]  = *(const bf16x8*)&As[(wm + f * 16 + (lane & 15)) * BK + pc * 8];
#pragma unroll
            for (int f = 0; f < 3; ++f)
                bfr[f] = *(const bf16x8*)&Bs[(wn + f * 16 + (lane & 15)) * BK + pc * 8];
#pragma unroll
            for (int fm = 0; fm < 4; ++fm)
#pragma unroll
                for (int fn = 0; fn < 3; ++fn)
                    acc[fm][fn] = __builtin_amdgcn_mfma_f32_16x16x32_bf16(
                        af[fm], bfr[fn], acc[fm][fn], 0, 0, 0);
        }
        __syncthreads();
    }

    // epilogue: D mapping col=lane&15, row=(lane>>4)*4+reg  [measured m89/m91]
    const int col   = lane & 15;
    const int rbase = (lane >> 4) * 4;
#pragma unroll
    for (int fm = 0; fm < 4; ++fm) {
#pragma unroll
        for (int fn = 0; fn < 3; ++fn) {
            const int j  = n0 + wn + fn * 16 + col;
            const float bj = bias[j];
#pragma unroll
            for (int r = 0; r < 4; ++r) {
                const int row = m0 + wm + fm * 16 + rbase + r;
                out[(size_t)row * JDIM + j] = acc[fm][fn][r] + bj;
            }
        }
    }
}

// ---------------- fallback (ws too small): slow but correct ----------------

__global__ __launch_bounds__(256)
void fallback_kernel(const float* __restrict__ x,
                     const float* __restrict__ coeffs,
                     const float* __restrict__ scale,
                     const float* __restrict__ shift,
                     float* __restrict__ out) {
    __shared__ float bas[KDIM];
    const int b = blockIdx.x;
    const int t = threadIdx.x;
    for (int i = t; i < IDIM; i += 256) {
        float tv = tanhf(x[(size_t)b * IDIM + i]);
#pragma unroll
        for (int g = 0; g < GRID; ++g) {
            float d = tv - (-1.0f + 0.5f * (float)g);
            bas[g * IDIM + i] = __expf(-5.0f * d * d);
        }
    }
    __syncthreads();
#pragma unroll
    for (int jj = 0; jj < 3; ++jj) {
        const int j = t + jj * 256;
        float acc = 0.f;
        for (int i = 0; i < IDIM; ++i) {
            const float sc = scale[(size_t)i * JDIM + j];
            const float* cp = &coeffs[((size_t)i * JDIM + j) * GRID];
            float s5 = 0.f;
#pragma unroll
            for (int g = 0; g < GRID; ++g) s5 += bas[g * IDIM + i] * cp[g];
            acc += s5 * sc + shift[(size_t)i * JDIM + j];
        }
        out[(size_t)b * JDIM + j] = acc;
    }
}

// ---------------- launch ----------------

extern "C" void kernel_launch(void* const* d_in, const int* in_sizes, int n_in,
                              void* d_out, int out_size, void* d_ws, size_t ws_size,
                              hipStream_t stream) {
    const float* x      = (const float*)d_in[0];
    const float* coeffs = (const float*)d_in[1];
    const float* scale  = (const float*)d_in[2];
    const float* shift  = (const float*)d_in[3];
    float* out = (float*)d_out;

    const size_t wt_bytes   = (size_t)JDIM * KDIM * sizeof(unsigned short); // 5,898,240
    const size_t bias_off   = wt_bytes;
    const size_t bias_bytes = (size_t)JDIM * sizeof(float);
    const size_t bas_off    = bias_off + bias_bytes;
    const size_t bas_bytes  = (size_t)BATCH * KDIM * sizeof(unsigned short);
    const size_t need       = bas_off + bas_bytes;                          // ~68.8 MB

    if (ws_size >= need) {
        unsigned short* Wt   = (unsigned short*)d_ws;
        float*          bias = (float*)((char*)d_ws + bias_off);
        unsigned short* Abas = (unsigned short*)((char*)d_ws + bas_off);

        hipMemsetAsync(bias, 0, bias_bytes, stream);
        wt_bias_kernel<<<(IDIM / WT_I) * (JDIM / WT_J), 256, 0, stream>>>(coeffs, scale, shift, Wt, bias);
        basis_kernel<<<(BATCH * (IDIM / 4)) / 256, 256, 0, stream>>>(x, Abas);
        kan_gemm<<<dim3(JDIM / BN, BATCH / BM), 256, 0, stream>>>(Abas, Wt, bias, out);
    } else {
        fallback_kernel<<<BATCH, 256, 0, stream>>>(x, coeffs, scale, shift, out);
    }
}